// Round 1
// baseline (580.059 us; speedup 1.0000x reference)
//
#include <hip/hip_runtime.h>
#include <hip/hip_bf16.h>

// dims
constexpr int BB = 16, IC = 512, OC = 512, HH = 64, WW = 64, HW = 64 * 64, SD = 512;
constexpr float MOD_SCALE = 0.04419417382415922f;      // 1/sqrt(512)
constexpr float CONV_SCALE = 0.014731391274719739f;    // 1/sqrt(512*9)
constexpr float CONV_SCALE2 = 2.170138888888889e-4f;   // 1/4608

typedef float f32x4 __attribute__((ext_vector_type(4)));
typedef short bf16x8 __attribute__((ext_vector_type(8)));

__device__ __forceinline__ unsigned short f2bf(float x) {
  __hip_bfloat16 h = __float2bfloat16(x);
  return *(unsigned short*)&h;
}

// ---------------- kernel 1: s[b][ic] = style @ (mod_weight*ms)^T + mod_bias ----
__global__ void k_style(const float* __restrict__ style, const float* __restrict__ mw,
                        const float* __restrict__ mb, float* __restrict__ s) {
  __shared__ float st[SD];
  const int b = blockIdx.x;
  for (int i = threadIdx.x; i < SD; i += 256) st[i] = style[b * SD + i];
  __syncthreads();
  for (int ic = threadIdx.x; ic < IC; ic += 256) {
    const float4* wr = (const float4*)(mw + (size_t)ic * SD);
    float acc = 0.f;
    for (int d = 0; d < SD / 4; ++d) {
      float4 w4 = wr[d];
      float4 s4 = *(const float4*)&st[d * 4];
      acc += w4.x * s4.x + w4.y * s4.y + w4.z * s4.z + w4.w * s4.w;
    }
    s[b * IC + ic] = acc * MOD_SCALE + mb[ic];
  }
}

// ---------------- kernel 2: pack weights [tap][oc][ic] bf16 + w2sum[oc][ic] ----
__global__ void k_pack(const float* __restrict__ w, unsigned short* __restrict__ wpack,
                       float* __restrict__ w2sum) {
  const int oc = blockIdx.x;
  const int ic0 = threadIdx.x * 2;
  const float* p = w + (size_t)oc * IC * 9 + (size_t)ic0 * 9;
  float v[18];
#pragma unroll
  for (int i = 0; i < 18; ++i) v[i] = p[i];
  float s0 = 0.f, s1 = 0.f;
#pragma unroll
  for (int t = 0; t < 9; ++t) { s0 += v[t] * v[t]; s1 += v[9 + t] * v[9 + t]; }
  *(float2*)&w2sum[oc * IC + ic0] = make_float2(s0, s1);
#pragma unroll
  for (int t = 0; t < 9; ++t) {
    unsigned int pk = (unsigned int)f2bf(v[t]) | ((unsigned int)f2bf(v[9 + t]) << 16);
    *(unsigned int*)&wpack[((size_t)t * OC + oc) * IC + ic0] = pk;
  }
}

// ---------------- kernel 3: fscale[b][oc] = conv_scale * rsqrt(cs2*sum + eps) --
__global__ void k_demod(const float* __restrict__ s, const float* __restrict__ w2sum,
                        float* __restrict__ fscale) {
  __shared__ float s2[IC];
  const int b = blockIdx.x;
  for (int i = threadIdx.x; i < IC; i += 256) { float v = s[b * IC + i]; s2[i] = v * v; }
  __syncthreads();
  for (int oc = threadIdx.x; oc < OC; oc += 256) {
    const float4* wr = (const float4*)(w2sum + (size_t)oc * IC);
    float acc = 0.f;
    for (int i4 = 0; i4 < IC / 4; ++i4) {
      float4 w4 = wr[i4];
      float4 q4 = *(const float4*)&s2[i4 * 4];
      acc += w4.x * q4.x + w4.y * q4.y + w4.z * q4.z + w4.w * q4.w;
    }
    fscale[b * OC + oc] = CONV_SCALE * rsqrtf(CONV_SCALE2 * acc + 1e-8f);
  }
}

// ---------------- kernel 4: the conv (implicit GEMM, bf16 MFMA) ----------------
// grid: 2048 = 16 b * 4 mblk * 32 nblk; block 256 (4 waves, 2x2 over 128x128 tile)
__global__ __launch_bounds__(256) void k_conv(
    const float* __restrict__ x, const unsigned short* __restrict__ wpack,
    const float* __restrict__ s, const float* __restrict__ fscale,
    float* __restrict__ out) {
  __shared__ __align__(128) unsigned short Asm[2][128 * 32];  // [buf][oc_local][ic] swizzled
  __shared__ __align__(128) unsigned short Bsm[264 * 32];     // [h''*66 + w''][ic] swizzled

  const int bx = blockIdx.x;
  const int b = bx >> 7;
  const int mblk = (bx >> 5) & 3;
  const int nblk = bx & 31;

  const int tid = threadIdx.x;
  const int wave = tid >> 6, lane = tid & 63;
  const int wm = wave >> 1, wn = wave & 1;
  const int lrow = lane & 15, lk = lane >> 4;

  const int h0 = nblk * 2;  // this block's 2 output rows; halo rows h0-1..h0+2
  const float* xb = x + (size_t)b * IC * HW;
  const float* sb = s + b * IC;

  f32x4 acc[4][4];
#pragma unroll
  for (int i = 0; i < 4; ++i)
#pragma unroll
    for (int j = 0; j < 4; ++j) acc[i][j] = f32x4{0.f, 0.f, 0.f, 0.f};

  // zero the w-halo rows (w''==0 and w''==65 for the 4 h rows), once
  {
    int q = tid >> 5;  // 0..7
    int hh = q >> 1, wz = (q & 1) ? 65 : 0;
    Bsm[(hh * 66 + wz) * 32 + (tid & 31)] = 0;
  }

  // stage input tile for one 32-ic block: [4 h rows][64 w][32 ic], scaled by s
  auto stageB = [&](int icb) {
    const int hh = wave;     // 0..3
    const int w = lane;      // 0..63
    const int h_abs = h0 - 1 + hh;
    const bool vh = (h_abs >= 0) && (h_abs < HH);
    const int h_safe = vh ? h_abs : 0;
    const int r = hh * 66 + w + 1;
    const int swz = (r >> 1) & 3;
    const float* src = xb + (size_t)(icb * 32) * HW + h_safe * WW + w;
#pragma unroll
    for (int c = 0; c < 4; ++c) {
      unsigned int pk[4];
#pragma unroll
      for (int jj = 0; jj < 4; ++jj) {
        int ic = c * 8 + jj * 2;
        float m0 = vh ? sb[icb * 32 + ic] : 0.f;
        float m1 = vh ? sb[icb * 32 + ic + 1] : 0.f;
        float v0 = src[(size_t)ic * HW] * m0;
        float v1 = src[(size_t)(ic + 1) * HW] * m1;
        pk[jj] = (unsigned int)f2bf(v0) | ((unsigned int)f2bf(v1) << 16);
      }
      int cd = c ^ swz;
      *(uint4*)&Bsm[r * 32 + cd * 8] = make_uint4(pk[0], pk[1], pk[2], pk[3]);
    }
  };

  // async-stage one 128x32 weight tile (bf16 copy, pre-swizzled global source)
  auto issueA = [&](int tap, int icb, int nb) {
    const unsigned short* base =
        wpack + ((size_t)(tap * OC + mblk * 128)) * IC + icb * 32;
#pragma unroll
    for (int q = 0; q < 2; ++q) {
      int r = wave * 32 + q * 16 + (lane >> 2);
      int c = lane & 3;
      int cs = c ^ ((r >> 1) & 3);
      const unsigned short* g = base + (size_t)r * IC + cs * 8;
      unsigned short* l = &Asm[nb][(wave * 32 + q * 16) * 32];
      __builtin_amdgcn_global_load_lds(
          (const __attribute__((address_space(1))) void*)g,
          (__attribute__((address_space(3))) void*)l, 16, 0, 0);
    }
  };

  stageB(0);
  issueA(0, 0, 0);
  __syncthreads();

  int cb = 0;
  for (int icb = 0; icb < 16; ++icb) {
#pragma unroll
    for (int t = 0; t < 9; ++t) {
      if (t < 8)          issueA(t + 1, icb, cb ^ 1);
      else if (icb < 15)  issueA(0, icb + 1, cb ^ 1);

      bf16x8 af[4], bfr[4];
#pragma unroll
      for (int i = 0; i < 4; ++i) {
        int r = wm * 64 + i * 16 + lrow;
        af[i] = *(const bf16x8*)&Asm[cb][r * 32 + ((lk ^ ((r >> 1) & 3)) * 8)];
      }
      const int dh = t / 3 - 1, dw = t % 3 - 1;
      const int hb = wn + dh + 1;
#pragma unroll
      for (int j = 0; j < 4; ++j) {
        int r = hb * 66 + j * 16 + lrow + dw + 1;
        bfr[j] = *(const bf16x8*)&Bsm[r * 32 + ((lk ^ ((r >> 1) & 3)) * 8)];
      }
#pragma unroll
      for (int i = 0; i < 4; ++i)
#pragma unroll
        for (int j = 0; j < 4; ++j)
          acc[i][j] =
              __builtin_amdgcn_mfma_f32_16x16x32_bf16(af[i], bfr[j], acc[i][j], 0, 0, 0);

      if (t == 8 && icb < 15) {
        __syncthreads();   // everyone done reading Bsm for this icb
        stageB(icb + 1);
      }
      __syncthreads();
      cb ^= 1;
    }
  }

  // epilogue: scale by conv_scale*demod[b][oc], coalesced 64B stores
  const float* fsb = fscale + b * OC;
#pragma unroll
  for (int i = 0; i < 4; ++i) {
#pragma unroll
    for (int rr = 0; rr < 4; ++rr) {
      const int oc = mblk * 128 + wm * 64 + i * 16 + lk * 4 + rr;
      const float sc = fsb[oc];
      float* orow = out + ((size_t)(b * OC + oc)) * HW + nblk * 128 + wn * 64 + lrow;
#pragma unroll
      for (int j = 0; j < 4; ++j) orow[j * 16] = acc[i][j][rr] * sc;
    }
  }
}

// ---------------- launch --------------------------------------------------------
extern "C" void kernel_launch(void* const* d_in, const int* in_sizes, int n_in,
                              void* d_out, int out_size, void* d_ws, size_t ws_size,
                              hipStream_t stream) {
  const float* input = (const float*)d_in[0];       // [16,512,64,64]
  const float* style = (const float*)d_in[1];       // [16,512]
  const float* weight = (const float*)d_in[2];      // [1,512,512,3,3]
  const float* mod_weight = (const float*)d_in[3];  // [512,512]
  const float* mod_bias = (const float*)d_in[4];    // [512]
  float* out = (float*)d_out;

  char* ws = (char*)d_ws;
  constexpr size_t WPACK_B = (size_t)9 * OC * IC * 2;   // 4,718,592
  constexpr size_t W2SUM_B = (size_t)OC * IC * 4;       // 1,048,576
  constexpr size_t S_B = (size_t)BB * IC * 4;           // 32,768
  unsigned short* wpack = (unsigned short*)ws;
  float* w2sum = (float*)(ws + WPACK_B);
  float* s = (float*)(ws + WPACK_B + W2SUM_B);
  float* fscale = (float*)(ws + WPACK_B + W2SUM_B + S_B);

  k_style<<<BB, 256, 0, stream>>>(style, mod_weight, mod_bias, s);
  k_pack<<<OC, 256, 0, stream>>>(weight, wpack, w2sum);
  k_demod<<<BB, 256, 0, stream>>>(s, w2sum, fscale);
  k_conv<<<2048, 256, 0, stream>>>(input, wpack, s, fscale, out);
}

// Round 2
// 471.301 us; speedup vs baseline: 1.2308x; 1.2308x over previous
//
#include <hip/hip_runtime.h>
#include <hip/hip_bf16.h>

// dims
constexpr int BB = 16, IC = 512, OC = 512, HH = 64, WW = 64, HW = 64 * 64, SD = 512;
constexpr float MOD_SCALE = 0.04419417382415922f;      // 1/sqrt(512)
constexpr float CONV_SCALE = 0.014731391274719739f;    // 1/sqrt(512*9)
constexpr float CONV_SCALE2 = 2.170138888888889e-4f;   // 1/4608

typedef float f32x4 __attribute__((ext_vector_type(4)));
typedef short bf16x8 __attribute__((ext_vector_type(8)));

__device__ __forceinline__ unsigned short f2bf(float x) {
  __hip_bfloat16 h = __float2bfloat16(x);
  return *(unsigned short*)&h;
}

// ---------------- kernel 1: s[b][ic] = style @ (mod_weight*ms)^T + mod_bias ----
__global__ void k_style(const float* __restrict__ style, const float* __restrict__ mw,
                        const float* __restrict__ mb, float* __restrict__ s) {
  __shared__ float st[SD];
  const int b = blockIdx.x;
  for (int i = threadIdx.x; i < SD; i += 256) st[i] = style[b * SD + i];
  __syncthreads();
  for (int ic = threadIdx.x; ic < IC; ic += 256) {
    const float4* wr = (const float4*)(mw + (size_t)ic * SD);
    float acc = 0.f;
    for (int d = 0; d < SD / 4; ++d) {
      float4 w4 = wr[d];
      float4 s4 = *(const float4*)&st[d * 4];
      acc += w4.x * s4.x + w4.y * s4.y + w4.z * s4.z + w4.w * s4.w;
    }
    s[b * IC + ic] = acc * MOD_SCALE + mb[ic];
  }
}

// ---------------- kernel 2: pack weights [tap][oc][ic] bf16 + w2sum[oc][ic] ----
__global__ void k_pack(const float* __restrict__ w, unsigned short* __restrict__ wpack,
                       float* __restrict__ w2sum) {
  const int oc = blockIdx.x;
  const int ic0 = threadIdx.x * 2;
  const float* p = w + (size_t)oc * IC * 9 + (size_t)ic0 * 9;
  float v[18];
#pragma unroll
  for (int i = 0; i < 18; ++i) v[i] = p[i];
  float s0 = 0.f, s1 = 0.f;
#pragma unroll
  for (int t = 0; t < 9; ++t) { s0 += v[t] * v[t]; s1 += v[9 + t] * v[9 + t]; }
  *(float2*)&w2sum[oc * IC + ic0] = make_float2(s0, s1);
#pragma unroll
  for (int t = 0; t < 9; ++t) {
    unsigned int pk = (unsigned int)f2bf(v[t]) | ((unsigned int)f2bf(v[9 + t]) << 16);
    *(unsigned int*)&wpack[((size_t)t * OC + oc) * IC + ic0] = pk;
  }
}

// ---------------- kernel 3: fscale[b][oc] = conv_scale * rsqrt(cs2*sum + eps) --
__global__ void k_demod(const float* __restrict__ s, const float* __restrict__ w2sum,
                        float* __restrict__ fscale) {
  __shared__ float s2[IC];
  const int b = blockIdx.x;
  for (int i = threadIdx.x; i < IC; i += 256) { float v = s[b * IC + i]; s2[i] = v * v; }
  __syncthreads();
  for (int oc = threadIdx.x; oc < OC; oc += 256) {
    const float4* wr = (const float4*)(w2sum + (size_t)oc * IC);
    float acc = 0.f;
    for (int i4 = 0; i4 < IC / 4; ++i4) {
      float4 w4 = wr[i4];
      float4 q4 = *(const float4*)&s2[i4 * 4];
      acc += w4.x * q4.x + w4.y * q4.y + w4.z * q4.z + w4.w * q4.w;
    }
    fscale[b * OC + oc] = CONV_SCALE * rsqrtf(CONV_SCALE2 * acc + 1e-8f);
  }
}

// ---------------- kernel 4: the conv (implicit GEMM, bf16 MFMA) ----------------
// grid: 2048 = 16 b * 4 mblk * 32 nblk; block 256 (4 waves, 2x2 over 128x128 tile)
// T3+T4 schedule: counted vmcnt + raw s_barrier per tap; vmcnt never drained to 0
// in the main loop. T5 setprio around the MFMA cluster.
__global__ __launch_bounds__(256) void k_conv(
    const float* __restrict__ x, const unsigned short* __restrict__ wpack,
    const float* __restrict__ s, const float* __restrict__ fscale,
    float* __restrict__ out) {
  __shared__ __align__(128) unsigned short Asm[2][128 * 32];  // [buf][oc_local][ic] swizzled
  __shared__ __align__(128) unsigned short Bsm[264 * 32];     // [h''*66 + w''][ic] swizzled

  const int bx = blockIdx.x;
  const int b = bx >> 7;
  const int mblk = (bx >> 5) & 3;
  const int nblk = bx & 31;

  const int tid = threadIdx.x;
  const int wave = tid >> 6, lane = tid & 63;
  const int wm = wave >> 1, wn = wave & 1;
  const int lrow = lane & 15, lk = lane >> 4;

  const int h0 = nblk * 2;  // this block's 2 output rows; halo rows h0-1..h0+2
  const float* xb = x + (size_t)b * IC * HW;
  const float* sb = s + b * IC;

  f32x4 acc[4][4];
#pragma unroll
  for (int i = 0; i < 4; ++i)
#pragma unroll
    for (int j = 0; j < 4; ++j) acc[i][j] = f32x4{0.f, 0.f, 0.f, 0.f};

  // zero the w-halo rows (w''==0 and w''==65 for the 4 h rows), once
  {
    int q = tid >> 5;  // 0..7
    int hh = q >> 1, wz = (q & 1) ? 65 : 0;
    Bsm[(hh * 66 + wz) * 32 + (tid & 31)] = 0;
  }

  // stage input tile for one 32-ic block: [4 h rows][64 w][32 ic], scaled by s
  auto stageB = [&](int icb) {
    const int hh = wave;     // 0..3
    const int w = lane;      // 0..63
    const int h_abs = h0 - 1 + hh;
    const bool vh = (h_abs >= 0) && (h_abs < HH);
    const int h_safe = vh ? h_abs : 0;
    const int r = hh * 66 + w + 1;
    const int swz = (r >> 1) & 3;
    const float* src = xb + (size_t)(icb * 32) * HW + h_safe * WW + w;
#pragma unroll
    for (int c = 0; c < 4; ++c) {
      unsigned int pk[4];
#pragma unroll
      for (int jj = 0; jj < 4; ++jj) {
        int ic = c * 8 + jj * 2;
        float m0 = vh ? sb[icb * 32 + ic] : 0.f;
        float m1 = vh ? sb[icb * 32 + ic + 1] : 0.f;
        float v0 = src[(size_t)ic * HW] * m0;
        float v1 = src[(size_t)(ic + 1) * HW] * m1;
        pk[jj] = (unsigned int)f2bf(v0) | ((unsigned int)f2bf(v1) << 16);
      }
      int cd = c ^ swz;
      *(uint4*)&Bsm[r * 32 + cd * 8] = make_uint4(pk[0], pk[1], pk[2], pk[3]);
    }
  };

  // async-stage one 128x32 weight tile (bf16 copy, pre-swizzled global source)
  // 2 global_load_lds per wave per call
  auto issueA = [&](int tap, int icb, int nb) {
    const unsigned short* base =
        wpack + ((size_t)(tap * OC + mblk * 128)) * IC + icb * 32;
#pragma unroll
    for (int q = 0; q < 2; ++q) {
      int r = wave * 32 + q * 16 + (lane >> 2);
      int c = lane & 3;
      int cs = c ^ ((r >> 1) & 3);
      const unsigned short* g = base + (size_t)r * IC + cs * 8;
      unsigned short* l = &Asm[nb][(wave * 32 + q * 16) * 32];
      __builtin_amdgcn_global_load_lds(
          (const __attribute__((address_space(1))) void*)g,
          (__attribute__((address_space(3))) void*)l, 16, 0, 0);
    }
  };

  stageB(0);
  issueA(0, 0, 0);
  __syncthreads();   // prologue: full drain once; outstanding vm = 0 here

  int cb = 0;
  for (int icb = 0; icb < 16; ++icb) {
#pragma unroll
    for (int t = 0; t < 9; ++t) {
      // ---- issue next A tile, then counted wait for current tile's arrival ----
      if (t < 8) {
        issueA(t + 1, icb, cb ^ 1);
        asm volatile("s_waitcnt vmcnt(2)" ::: "memory");
      } else if (icb < 15) {
        issueA(0, icb + 1, cb ^ 1);
        asm volatile("s_waitcnt vmcnt(2)" ::: "memory");
      } else {
        asm volatile("s_waitcnt vmcnt(0)" ::: "memory");  // last tap: no prefetch in flight behind it
      }
      __builtin_amdgcn_s_barrier();          // arrival barrier (raw: no vmcnt drain)
      __builtin_amdgcn_sched_barrier(0);

      bf16x8 af[4], bfr[4];
#pragma unroll
      for (int i = 0; i < 4; ++i) {
        int r = wm * 64 + i * 16 + lrow;
        af[i] = *(const bf16x8*)&Asm[cb][r * 32 + ((lk ^ ((r >> 1) & 3)) * 8)];
      }
      const int dh = t / 3 - 1, dw = t % 3 - 1;
      const int hb = wn + dh + 1;
#pragma unroll
      for (int j = 0; j < 4; ++j) {
        int r = hb * 66 + j * 16 + lrow + dw + 1;
        bfr[j] = *(const bf16x8*)&Bsm[r * 32 + ((lk ^ ((r >> 1) & 3)) * 8)];
      }
      __builtin_amdgcn_s_setprio(1);
#pragma unroll
      for (int i = 0; i < 4; ++i)
#pragma unroll
        for (int j = 0; j < 4; ++j)
          acc[i][j] =
              __builtin_amdgcn_mfma_f32_16x16x32_bf16(af[i], bfr[j], acc[i][j], 0, 0, 0);
      __builtin_amdgcn_s_setprio(0);
      __builtin_amdgcn_sched_barrier(0);
      __builtin_amdgcn_s_barrier();          // read-completion barrier (buffer reuse safe)
      cb ^= 1;
    }
    if (icb < 15) {
      stageB(icb + 1);   // compiler-tracked loads self-drain older DMA (FIFO vmcnt)
      __syncthreads();   // once per icb: full drain + lgkm for the ds_writes
    }
  }

  // epilogue: scale by conv_scale*demod[b][oc], coalesced 64B stores
  const float* fsb = fscale + b * OC;
#pragma unroll
  for (int i = 0; i < 4; ++i) {
#pragma unroll
    for (int rr = 0; rr < 4; ++rr) {
      const int oc = mblk * 128 + wm * 64 + i * 16 + lk * 4 + rr;
      const float sc = fsb[oc];
      float* orow = out + ((size_t)(b * OC + oc)) * HW + nblk * 128 + wn * 64 + lrow;
#pragma unroll
      for (int j = 0; j < 4; ++j) orow[j * 16] = acc[i][j][rr] * sc;
    }
  }
}

// ---------------- launch --------------------------------------------------------
extern "C" void kernel_launch(void* const* d_in, const int* in_sizes, int n_in,
                              void* d_out, int out_size, void* d_ws, size_t ws_size,
                              hipStream_t stream) {
  const float* input = (const float*)d_in[0];       // [16,512,64,64]
  const float* style = (const float*)d_in[1];       // [16,512]
  const float* weight = (const float*)d_in[2];      // [1,512,512,3,3]
  const float* mod_weight = (const float*)d_in[3];  // [512,512]
  const float* mod_bias = (const float*)d_in[4];    // [512]
  float* out = (float*)d_out;

  char* ws = (char*)d_ws;
  constexpr size_t WPACK_B = (size_t)9 * OC * IC * 2;   // 4,718,592
  constexpr size_t W2SUM_B = (size_t)OC * IC * 4;       // 1,048,576
  constexpr size_t S_B = (size_t)BB * IC * 4;           // 32,768
  unsigned short* wpack = (unsigned short*)ws;
  float* w2sum = (float*)(ws + WPACK_B);
  float* s = (float*)(ws + WPACK_B + W2SUM_B);
  float* fscale = (float*)(ws + WPACK_B + W2SUM_B + S_B);

  k_style<<<BB, 256, 0, stream>>>(style, mod_weight, mod_bias, s);
  k_pack<<<OC, 256, 0, stream>>>(weight, wpack, w2sum);
  k_demod<<<BB, 256, 0, stream>>>(s, w2sum, fscale);
  k_conv<<<2048, 256, 0, stream>>>(input, wpack, s, fscale, out);
}